// Round 5
// baseline (16473.360 us; speedup 1.0000x reference)
//
#include <hip/hip_runtime.h>
#include <hip/hip_bf16.h>

#define TT 512
#define BB 64
#define HH 128
#define GG 512   // 4*H
#define TBH (TT*BB*HH)
#define TBG (TT*BB*GG)
#define BH (BB*HH)
#define CH 64                 // wavefront chunk length (timesteps)
#define NCH (TT/CH)           // 8 chunks
#define CHGG (CH*BB*GG)       // floats per xg chunk slot
#define CHH (CH*BB*HH)        // floats per out chunk

__device__ __forceinline__ float bflo(unsigned u) { return __uint_as_float(u << 16); }
__device__ __forceinline__ float bfhi(unsigned u) { return __uint_as_float(u & 0xffff0000u); }
__device__ __forceinline__ float ldf(const void* p, size_t i, int isbf) {
  return isbf ? __uint_as_float(((unsigned)((const unsigned short*)p)[i]) << 16)
              : ((const float*)p)[i];
}

template<int CTRL>
__device__ __forceinline__ float dpp_add(float v) {
  int r = __builtin_amdgcn_mov_dpp(__float_as_int(v), CTRL, 0xF, 0xF, true);
  return v + __int_as_float(r);
}

__device__ __forceinline__ float sigm(float x) {
  return __builtin_amdgcn_rcpf(1.f + __expf(-x));
}
__device__ __forceinline__ float tanh_f(float x) {
  return fmaf(2.f, __builtin_amdgcn_rcpf(1.f + __expf(-2.f * x)), -1.f);
}

__global__ __launch_bounds__(256) void k_detect(const unsigned* __restrict__ bits,
                                                unsigned* __restrict__ flag) {
  __shared__ int cnt;
  if (threadIdx.x == 0) cnt = 0;
  __syncthreads();
  int local = 0;
  for (int i = threadIdx.x; i < 1024; i += 256) {
    unsigned e = (bits[i] >> 7) & 0xff;
    if (e >= 118 && e <= 134) local++;
  }
  atomicAdd(&cnt, local);
  __syncthreads();
  if (threadIdx.x == 0) *flag = (cnt > 768) ? 1u : 0u;
}

__global__ __launch_bounds__(256) void k_embed(const int* __restrict__ idx,
                                               const void* __restrict__ emb,
                                               const unsigned* __restrict__ flag,
                                               float* __restrict__ x0) {
  int isbf = (int)*flag;
  int i = blockIdx.x * 256 + threadIdx.x;
  int h = i & (HH - 1);
  int tb = i >> 7;
  x0[i] = ldf(emb, (size_t)idx[tb] * HH + h, isbf);
}

// C[M,512] = A[M,K] @ W[512,K]^T + bias ; grid (M/64, 8)   (L0 + fallback path)
__global__ __launch_bounds__(256) void k_proj(const float* __restrict__ A,
                                              const void* __restrict__ W, size_t w_off,
                                              const void* __restrict__ bias, size_t b_off,
                                              float* __restrict__ C, int K,
                                              const unsigned* __restrict__ flag) {
  int isbf = (int)*flag;
  __shared__ float As[16][68];
  __shared__ float Bs[16][68];
  int tid = threadIdx.x;
  int tx = tid & 15, ty = tid >> 4;
  int m_base = blockIdx.x * 64, n_base = blockIdx.y * 64;
  float acc[4][4] = {};
  int kk = tid & 15, rr = tid >> 4;
  for (int k0 = 0; k0 < K; k0 += 16) {
    #pragma unroll
    for (int r = 0; r < 4; r++) {
      As[kk][rr + 16*r] = A[(size_t)(m_base + rr + 16*r) * K + k0 + kk];
      Bs[kk][rr + 16*r] = ldf(W, w_off + (size_t)(n_base + rr + 16*r) * K + k0 + kk, isbf);
    }
    __syncthreads();
    #pragma unroll
    for (int k = 0; k < 16; k++) {
      float4 av = *(const float4*)(&As[k][ty*4]);
      float4 bv = *(const float4*)(&Bs[k][tx*4]);
      float a[4] = {av.x, av.y, av.z, av.w};
      float b[4] = {bv.x, bv.y, bv.z, bv.w};
      #pragma unroll
      for (int i = 0; i < 4; i++)
        #pragma unroll
        for (int j = 0; j < 4; j++)
          acc[i][j] += a[i] * b[j];
    }
    __syncthreads();
  }
  #pragma unroll
  for (int i = 0; i < 4; i++) {
    #pragma unroll
    for (int j = 0; j < 4; j++) {
      int n = n_base + tx*4 + j;
      C[(size_t)(m_base + ty*4 + i) * GG + n] = acc[i][j] + ldf(bias, b_off + n, isbf);
    }
  }
}

// L0 + fallback recurrent kernel (full-T). One block per (batch, direction).
__global__ __launch_bounds__(512, 2) void k_recur(
    const float* __restrict__ xg, size_t xg_dstride,
    const void* __restrict__ whh, size_t w_off, size_t w_dstride,
    float* __restrict__ hout, int hout_stride, int hout_doff,
    const float* __restrict__ res,
    float* __restrict__ hfin, float* __restrict__ cfin,
    int bidir, const unsigned* __restrict__ flag) {
  int isbf = (int)*flag;
  int d = blockIdx.x >> 6;
  int b = blockIdx.x & 63;
  int dir = (bidir == 2 || (bidir == 1 && d)) ? -1 : 1;
  xg += (size_t)d * xg_dstride;
  size_t woff = w_off + (size_t)d * w_dstride;
  int hcol = hout_doff * d;

  int t0 = threadIdx.x;
  int j = t0 >> 2, q = t0 & 3;

  // W_hh fragment, rotated by q chunks for bank-conflict-free broadcast reads
  float w[4][32];
  size_t wbase = woff + (size_t)j * HH + q * 32;
  if (isbf) {
    const uint4* wp = (const uint4*)whh;
    #pragma unroll
    for (int g = 0; g < 4; g++) {
      size_t b8 = (wbase + (size_t)g * 128 * HH) >> 3;
      #pragma unroll
      for (int u = 0; u < 4; u++) {
        uint4 v = wp[b8 + ((u + q) & 3)];
        w[g][u*8+0] = bflo(v.x); w[g][u*8+1] = bfhi(v.x);
        w[g][u*8+2] = bflo(v.y); w[g][u*8+3] = bfhi(v.y);
        w[g][u*8+4] = bflo(v.z); w[g][u*8+5] = bfhi(v.z);
        w[g][u*8+6] = bflo(v.w); w[g][u*8+7] = bfhi(v.w);
      }
    }
  } else {
    const float4* wp = (const float4*)whh;
    #pragma unroll
    for (int g = 0; g < 4; g++) {
      size_t b4 = (wbase + (size_t)g * 128 * HH) >> 2;
      #pragma unroll
      for (int u = 0; u < 8; u++) {
        float4 v = wp[b4 + ((u + 2*q) & 7)];
        w[g][u*4+0] = v.x; w[g][u*4+1] = v.y; w[g][u*4+2] = v.z; w[g][u*4+3] = v.w;
      }
    }
  }

  __shared__ float h_lds[2][HH];
  if (t0 < HH) h_lds[0][t0] = 0.f;
  float c = 0.f;

  int tfirst = (dir > 0) ? 0 : (TT - 1);
  size_t rg0 = ((size_t)tfirst * BB + b) * GG;
  float xg_cur[4];
  #pragma unroll
  for (int g = 0; g < 4; g++) xg_cur[g] = xg[rg0 + g * HH + j];
  float res_cur = res ? res[((size_t)tfirst * BB + b) * HH + j] : 0.f;
  __syncthreads();

  const float* hc = h_lds[0];
  float* hn = h_lds[1];

  #pragma unroll 1
  for (int s = 0; s < TT; s++) {
    int t = (dir > 0) ? s : (TT - 1 - s);
    float xg_nxt[4] = {0.f, 0.f, 0.f, 0.f};
    float res_nxt = 0.f;
    if (s + 1 < TT) {
      int tn = (dir > 0) ? (s + 1) : (TT - 2 - s);
      size_t rg = ((size_t)tn * BB + b) * GG;
      #pragma unroll
      for (int g = 0; g < 4; g++) xg_nxt[g] = xg[rg + g * HH + j];
      if (res) res_nxt = res[((size_t)tn * BB + b) * HH + j];
    }
    float p0 = 0.f, p1 = 0.f, p2 = 0.f, p3 = 0.f;
    const float4* hq = (const float4*)(hc + (q << 5));
    #pragma unroll
    for (int u = 0; u < 8; u++) {
      float4 hv = hq[(u + 2*q) & 7];
      p0 = fmaf(w[0][u*4+0], hv.x, p0); p0 = fmaf(w[0][u*4+1], hv.y, p0);
      p0 = fmaf(w[0][u*4+2], hv.z, p0); p0 = fmaf(w[0][u*4+3], hv.w, p0);
      p1 = fmaf(w[1][u*4+0], hv.x, p1); p1 = fmaf(w[1][u*4+1], hv.y, p1);
      p1 = fmaf(w[1][u*4+2], hv.z, p1); p1 = fmaf(w[1][u*4+3], hv.w, p1);
      p2 = fmaf(w[2][u*4+0], hv.x, p2); p2 = fmaf(w[2][u*4+1], hv.y, p2);
      p2 = fmaf(w[2][u*4+2], hv.z, p2); p2 = fmaf(w[2][u*4+3], hv.w, p2);
      p3 = fmaf(w[3][u*4+0], hv.x, p3); p3 = fmaf(w[3][u*4+1], hv.y, p3);
      p3 = fmaf(w[3][u*4+2], hv.z, p3); p3 = fmaf(w[3][u*4+3], hv.w, p3);
    }
    p0 = dpp_add<0xB1>(p0); p0 = dpp_add<0x4E>(p0);
    p1 = dpp_add<0xB1>(p1); p1 = dpp_add<0x4E>(p1);
    p2 = dpp_add<0xB1>(p2); p2 = dpp_add<0x4E>(p2);
    p3 = dpp_add<0xB1>(p3); p3 = dpp_add<0x4E>(p3);

    float gi = p0 + xg_cur[0], gf = p1 + xg_cur[1];
    float gc = p2 + xg_cur[2], go = p3 + xg_cur[3];
    float si = sigm(gi), sf = sigm(gf), so = sigm(go);
    c = fmaf(sf, c, si * tanh_f(gc));
    float h = so * tanh_f(c);

    if (q == 0) {
      hn[j] = h;
      hout[((size_t)t * BB + b) * hout_stride + hcol + j] = h + res_cur;
      if (t == TT - 1) hfin[(size_t)(d * BB + b) * HH + j] = h;
    }
    #pragma unroll
    for (int g = 0; g < 4; g++) xg_cur[g] = xg_nxt[g];
    res_cur = res_nxt;
    __syncthreads();
    const float* tmp = hc; hc = hn; hn = (float*)tmp;
  }
  if (q == 0) cfin[(size_t)(d * BB + b) * HH + j] = c;
}

// ---------------- wavefront kernel: layers 1..7, chunked, lag-1 ----------------
// Cell recur(r,k) at wave r-1+k (waves 0..13). Per block (one (cell, batch)):
//   [r==1]  prologue: xg(1,k) = xcat_chunk @ w_ih1^T + b1  -> scratch (block-local life)
//   recur: 64 steps; writes out chunk (ring / out7), fills hchunk[64][HH] in LDS
//   [r<7]   epilogue: xg(r+1,k) = hchunk @ w_ih(r+1)^T + b -> slot (layer,parity keyed)
// GEMMs are lane-owns-column: thread t owns output col n=t, W row n in 32 float4 regs,
// A read from LDS via broadcast (all lanes same addr) -> no barriers, FMA-bound.
// Slot safety: xg(r,k) live waves [r-2+k, r-1+k]; same (layer,parity) slot's next writer
// comes one wave after the previous reader. Rings analogous. Scratch (x0 chunks 4..7)
// last used wave 7; out7 chunk 4 first written wave 10.
struct WaveDesc { int n; int r[8]; int k[8]; };

__global__ __launch_bounds__(512, 2) void k_wave(
    WaveDesc wd, float* __restrict__ xgf, float* __restrict__ xgb,
    const float* __restrict__ xcat, float* __restrict__ out7, float* __restrict__ scratch,
    const void* __restrict__ w_ih1, const void* __restrict__ w_hh1, const void* __restrict__ b1,
    const void* __restrict__ w_ihr, const void* __restrict__ w_hhr, const void* __restrict__ br,
    const unsigned* __restrict__ flag) {
  int isbf = (int)*flag;
  int slot = blockIdx.x >> 6;
  int b = blockIdx.x & 63;
  int r = wd.r[slot];
  int k = wd.k[slot];

  float* ringbase = xgb + 4 * (size_t)CHGG;          // 12 x CHH (layers 1..6, ring-2)
  float* hstate   = ringbase + 12 * (size_t)CHH;     // [7][BB][HH]
  float* cstate   = hstate + 7 * (size_t)BH;

  auto xgslot = [&](int rr, int kk) -> float* {      // rr in [2,7]
    int s = (rr - 2) * 2 + (kk & 1);
    return (s < 8) ? (xgf + (size_t)s * CHGG) : (xgb + (size_t)(s - 8) * CHGG);
  };
  auto ringch = [&](int rr, int kk) -> float* {      // rr in [1,6]
    return ringbase + ((size_t)(rr - 1) * 2 + (kk & 1)) * CHH;
  };

  __shared__ float hchunk[CH][132];   // padded; A-matrix for prologue/epilogue GEMMs
  __shared__ float h_lds[2][HH];

  int t0 = threadIdx.x;
  int nn = t0;                        // this thread's GEMM output column (0..511)

  // -------- layer-1 prologue: xg(1,k) -> scratch (K=256, two halves w/ global acc) --------
  if (r == 1) {
    float* dst = scratch + (size_t)b * GG + nn;
    for (int kh = 0; kh < 2; kh++) {
      {
        int m = t0 >> 3, c0 = (t0 & 7) * 16;
        const float* src = xcat + ((size_t)(k * CH + m) * BB + b) * (2 * HH) + kh * HH + c0;
        #pragma unroll
        for (int u = 0; u < 4; u++)
          *(float4*)&hchunk[m][c0 + u * 4] = ((const float4*)src)[u];
      }
      __syncthreads();
      float4 wr4[32];
      if (isbf) {
        const uint4* wp = (const uint4*)w_ih1;
        size_t base8 = ((size_t)nn * (2 * HH) + (size_t)kh * HH) >> 3;
        #pragma unroll
        for (int u = 0; u < 16; u++) {
          uint4 v = wp[base8 + u];
          wr4[u*2+0] = make_float4(bflo(v.x), bfhi(v.x), bflo(v.y), bfhi(v.y));
          wr4[u*2+1] = make_float4(bflo(v.z), bfhi(v.z), bflo(v.w), bfhi(v.w));
        }
      } else {
        const float4* wp = (const float4*)w_ih1;
        size_t base4 = ((size_t)nn * (2 * HH) + (size_t)kh * HH) >> 2;
        #pragma unroll
        for (int u = 0; u < 32; u++) wr4[u] = wp[base4 + u];
      }
      float bias = (kh == 1) ? ldf(b1, nn, isbf) : 0.f;
      #pragma unroll 2
      for (int m = 0; m < CH; m++) {
        float a = 0.f;
        #pragma unroll
        for (int u = 0; u < 32; u++) {
          float4 hv = *(const float4*)&hchunk[m][u * 4];
          a = fmaf(wr4[u].x, hv.x, a); a = fmaf(wr4[u].y, hv.y, a);
          a = fmaf(wr4[u].z, hv.z, a); a = fmaf(wr4[u].w, hv.w, a);
        }
        size_t off = (size_t)m * BB * GG;
        if (kh == 0) dst[off] = a;
        else         dst[off] = dst[off] + a + bias;
      }
      __syncthreads();
    }
  }

  // -------- recur: chunk k of layer r --------
  const void* whh = (r == 1) ? w_hh1 : w_hhr;
  size_t woff = (r == 1) ? 0 : (size_t)(r - 2) * GG * HH;
  const float* xg = (r == 1) ? scratch : xgslot(r, k);
  const float* resb = (r >= 2) ? (ringch(r - 1, k) + (size_t)b * HH) : nullptr;
  float* houtb = (r == 7) ? (out7 + (size_t)k * CHH + (size_t)b * HH)
                          : (ringch(r, k) + (size_t)b * HH);
  float* hst = hstate + (size_t)(r - 1) * BH + (size_t)b * HH;
  float* cst = cstate + (size_t)(r - 1) * BH + (size_t)b * HH;

  int j = t0 >> 2, q = t0 & 3;

  float w[4][32];
  size_t wbase = woff + (size_t)j * HH + q * 32;
  if (isbf) {
    const uint4* wp = (const uint4*)whh;
    #pragma unroll
    for (int g = 0; g < 4; g++) {
      size_t b8 = (wbase + (size_t)g * 128 * HH) >> 3;
      #pragma unroll
      for (int u = 0; u < 4; u++) {
        uint4 v = wp[b8 + ((u + q) & 3)];
        w[g][u*8+0] = bflo(v.x); w[g][u*8+1] = bfhi(v.x);
        w[g][u*8+2] = bflo(v.y); w[g][u*8+3] = bfhi(v.y);
        w[g][u*8+4] = bflo(v.z); w[g][u*8+5] = bfhi(v.z);
        w[g][u*8+6] = bflo(v.w); w[g][u*8+7] = bfhi(v.w);
      }
    }
  } else {
    const float4* wp = (const float4*)whh;
    #pragma unroll
    for (int g = 0; g < 4; g++) {
      size_t b4 = (wbase + (size_t)g * 128 * HH) >> 2;
      #pragma unroll
      for (int u = 0; u < 8; u++) {
        float4 v = wp[b4 + ((u + 2*q) & 7)];
        w[g][u*4+0] = v.x; w[g][u*4+1] = v.y; w[g][u*4+2] = v.z; w[g][u*4+3] = v.w;
      }
    }
  }

  if (t0 < HH) h_lds[0][t0] = k ? hst[t0] : 0.f;
  float c = k ? cst[j] : 0.f;

  size_t rg0 = (size_t)b * GG;  // t_loc = 0
  float xg_cur[4];
  #pragma unroll
  for (int g = 0; g < 4; g++) xg_cur[g] = xg[rg0 + g * HH + j];
  float res_cur = resb ? resb[j] : 0.f;
  __syncthreads();

  const float* hc = h_lds[0];
  float* hn = h_lds[1];

  #pragma unroll 1
  for (int s = 0; s < CH; s++) {
    float xg_nxt[4] = {0.f, 0.f, 0.f, 0.f};
    float res_nxt = 0.f;
    if (s + 1 < CH) {
      size_t rg = ((size_t)(s + 1) * BB + b) * GG;
      #pragma unroll
      for (int g = 0; g < 4; g++) xg_nxt[g] = xg[rg + g * HH + j];
      if (resb) res_nxt = resb[(size_t)(s + 1) * BB * HH + j];
    }
    float p0 = 0.f, p1 = 0.f, p2 = 0.f, p3 = 0.f;
    const float4* hq = (const float4*)(hc + (q << 5));
    #pragma unroll
    for (int u = 0; u < 8; u++) {
      float4 hv = hq[(u + 2*q) & 7];
      p0 = fmaf(w[0][u*4+0], hv.x, p0); p0 = fmaf(w[0][u*4+1], hv.y, p0);
      p0 = fmaf(w[0][u*4+2], hv.z, p0); p0 = fmaf(w[0][u*4+3], hv.w, p0);
      p1 = fmaf(w[1][u*4+0], hv.x, p1); p1 = fmaf(w[1][u*4+1], hv.y, p1);
      p1 = fmaf(w[1][u*4+2], hv.z, p1); p1 = fmaf(w[1][u*4+3], hv.w, p1);
      p2 = fmaf(w[2][u*4+0], hv.x, p2); p2 = fmaf(w[2][u*4+1], hv.y, p2);
      p2 = fmaf(w[2][u*4+2], hv.z, p2); p2 = fmaf(w[2][u*4+3], hv.w, p2);
      p3 = fmaf(w[3][u*4+0], hv.x, p3); p3 = fmaf(w[3][u*4+1], hv.y, p3);
      p3 = fmaf(w[3][u*4+2], hv.z, p3); p3 = fmaf(w[3][u*4+3], hv.w, p3);
    }
    p0 = dpp_add<0xB1>(p0); p0 = dpp_add<0x4E>(p0);
    p1 = dpp_add<0xB1>(p1); p1 = dpp_add<0x4E>(p1);
    p2 = dpp_add<0xB1>(p2); p2 = dpp_add<0x4E>(p2);
    p3 = dpp_add<0xB1>(p3); p3 = dpp_add<0x4E>(p3);

    float gi = p0 + xg_cur[0], gf = p1 + xg_cur[1];
    float gc = p2 + xg_cur[2], go = p3 + xg_cur[3];
    float si = sigm(gi), sf = sigm(gf), so = sigm(go);
    c = fmaf(sf, c, si * tanh_f(gc));
    float h = so * tanh_f(c);

    if (q == 0) {
      float hv = h + res_cur;
      hn[j] = h;
      hchunk[s][j] = hv;
      houtb[(size_t)s * BB * HH + j] = hv;
      if (s == CH - 1) hst[j] = h;   // raw h for next chunk's state
    }
    #pragma unroll
    for (int g = 0; g < 4; g++) xg_cur[g] = xg_nxt[g];
    res_cur = res_nxt;
    __syncthreads();
    const float* tmp = hc; hc = hn; hn = (float*)tmp;
  }
  if (q == 0) cst[j] = c;

  // -------- epilogue: xg(r+1,k) = hchunk @ w_ih(r+1)^T + b  (K=128, no barriers) --------
  if (r < 7) {
    float* dst = xgslot(r + 1, k) + (size_t)b * GG + nn;
    float4 wr4[32];
    if (isbf) {
      const uint4* wp = (const uint4*)w_ihr;
      size_t base8 = ((size_t)(r - 1) * GG * HH + (size_t)nn * HH) >> 3;
      #pragma unroll
      for (int u = 0; u < 16; u++) {
        uint4 v = wp[base8 + u];
        wr4[u*2+0] = make_float4(bflo(v.x), bfhi(v.x), bflo(v.y), bfhi(v.y));
        wr4[u*2+1] = make_float4(bflo(v.z), bfhi(v.z), bflo(v.w), bfhi(v.w));
      }
    } else {
      const float4* wp = (const float4*)w_ihr;
      size_t base4 = ((size_t)(r - 1) * GG * HH + (size_t)nn * HH) >> 2;
      #pragma unroll
      for (int u = 0; u < 32; u++) wr4[u] = wp[base4 + u];
    }
    float bias = ldf(br, (size_t)(r - 1) * GG + nn, isbf);
    #pragma unroll 2
    for (int m = 0; m < CH; m++) {
      float a = bias;
      #pragma unroll
      for (int u = 0; u < 32; u++) {
        float4 hv = *(const float4*)&hchunk[m][u * 4];
        a = fmaf(wr4[u].x, hv.x, a); a = fmaf(wr4[u].y, hv.y, a);
        a = fmaf(wr4[u].z, hv.z, a); a = fmaf(wr4[u].w, hv.w, a);
      }
      dst[(size_t)m * BB * GG] = a;
    }
  }
}

__global__ __launch_bounds__(256) void k_out(const float* __restrict__ x,
                                             const float* __restrict__ hfin,
                                             const float* __restrict__ cfin,
                                             void* __restrict__ out,
                                             const unsigned* __restrict__ flag) {
  int isbf = (int)*flag;
  int i = blockIdx.x * 256 + threadIdx.x;
  float v;
  if (i < TBH) v = x[i];
  else if (i < TBH + BH) v = hfin[i - TBH];
  else v = cfin[i - TBH - BH];
  if (isbf) ((__hip_bfloat16*)out)[i] = __float2bfloat16(v);
  else ((float*)out)[i] = v;
}

extern "C" void kernel_launch(void* const* d_in, const int* in_sizes, int n_in,
                              void* d_out, int out_size, void* d_ws, size_t ws_size,
                              hipStream_t stream) {
  const int* idx = (const int*)d_in[0];
  const void* emb   = d_in[1];
  const void* w_ih0 = d_in[2];
  const void* w_hh0 = d_in[3];
  const void* b0    = d_in[4];
  const void* w_ih1 = d_in[5];
  const void* w_hh1 = d_in[6];
  const void* b1    = d_in[7];
  const void* w_ihr = d_in[8];
  const void* w_hhr = d_in[9];
  const void* br    = d_in[10];

  float* ws   = (float*)d_ws;
  float* x0   = ws;                       // TBH   (L0 input; later out7; chunks 4..7 = scratch)
  float* xcat = ws + TBH;                 // 2*TBH (L0 output / L1 input, live through wave 7)
  float* xg_f = ws + 3 * (size_t)TBH;     // TBG   (L0 fwd xg; later xg slots 0..7)
  float* hfin = ws + 3 * (size_t)TBH + TBG;        // 2*BH
  float* cfin = hfin + 2 * BH;                     // 2*BH
  unsigned* flag = (unsigned*)(cfin + 2 * BH);
  float* xg_b = cfin + 2 * BH + 16384;    // TBG (L0 bwd xg; later slots 8..11 + rings + states)
  int merged = ws_size >= (size_t)(3 * (size_t)TBH + 2 * (size_t)TBG + 4 * BH + 16384 + 64) * 4;

  k_detect<<<1, 256, 0, stream>>>((const unsigned*)emb, flag);
  k_embed<<<TBH / 256, 256, 0, stream>>>(idx, emb, flag, x0);

  dim3 pg(512, 8);
  if (merged) {
    // ---- layer 0 (bidirectional) ----
    k_proj<<<pg, 256, 0, stream>>>(x0, w_ih0, 0, b0, 0, xg_f, HH, flag);
    k_proj<<<pg, 256, 0, stream>>>(x0, w_ih0, (size_t)GG * HH, b0, GG, xg_b, HH, flag);
    k_recur<<<128, 512, 0, stream>>>(xg_f, (size_t)(xg_b - xg_f), w_hh0, 0, (size_t)GG * HH,
                                     xcat, 2 * HH, HH, nullptr, hfin, cfin, 1, flag);

    // ---- layers 1..7: lag-1 wavefront ----
    float* scratch = x0 + (size_t)TBH / 2;             // = one CHGG, aliases out7 chunks 4..7
    float* ringbase = xg_b + 4 * (size_t)CHGG;
    float* hstate  = ringbase + 12 * (size_t)CHH;
    float* cstate  = hstate + 7 * (size_t)BH;
    for (int wv = 0; wv <= 6 + (NCH - 1); wv++) {
      WaveDesc wd; wd.n = 0;
      for (int r = 1; r <= 7; r++) {                   // r ascending: layer-1 (heaviest) first
        int kk = wv - (r - 1);
        if (kk >= 0 && kk < NCH) { wd.r[wd.n] = r; wd.k[wd.n] = kk; wd.n++; }
      }
      if (wd.n)
        k_wave<<<wd.n * 64, 512, 0, stream>>>(wd, xg_f, xg_b, xcat, x0, scratch,
                                              w_ih1, w_hh1, b1, w_ihr, w_hhr, br, flag);
    }
    k_out<<<(TBH + 2 * BH) / 256, 256, 0, stream>>>(x0, hstate + 6 * BH, cstate + 6 * BH,
                                                    d_out, flag);
  } else {
    // ---- fallback: original fully-serial path ----
    k_proj<<<pg, 256, 0, stream>>>(x0, w_ih0, 0, b0, 0, xg_f, HH, flag);
    k_recur<<<64, 512, 0, stream>>>(xg_f, 0, w_hh0, 0, 0,
                                    xcat, 2 * HH, 0, nullptr, hfin, cfin, 0, flag);
    k_proj<<<pg, 256, 0, stream>>>(x0, w_ih0, (size_t)GG * HH, b0, GG, xg_f, HH, flag);
    k_recur<<<64, 512, 0, stream>>>(xg_f, 0, w_hh0, (size_t)GG * HH, 0,
                                    xcat + HH, 2 * HH, 0, nullptr, hfin, cfin, 2, flag);
    float* xA = xcat;
    float* xB = xcat + TBH;
    k_proj<<<pg, 256, 0, stream>>>(xcat, w_ih1, 0, b1, 0, xg_f, 2 * HH, flag);
    k_recur<<<64, 512, 0, stream>>>(xg_f, 0, w_hh1, 0, 0, xA, HH, 0, nullptr, hfin, cfin, 0, flag);
    float* cur = xA;
    float* nxt = xB;
    for (int r = 0; r < 6; r++) {
      k_proj<<<pg, 256, 0, stream>>>(cur, w_ihr, (size_t)r * GG * HH, br, (size_t)r * GG, xg_f, HH, flag);
      k_recur<<<64, 512, 0, stream>>>(xg_f, 0, w_hhr, (size_t)r * GG * HH, 0,
                                      nxt, HH, 0, cur, hfin, cfin, 0, flag);
      float* t = cur; cur = nxt; nxt = t;
    }
    k_out<<<(TBH + 2 * BH) / 256, 256, 0, stream>>>(cur, hfin, cfin, d_out, flag);
  }
}

// Round 6
// 2641.703 us; speedup vs baseline: 6.2359x; 6.2359x over previous
//
#include <hip/hip_runtime.h>
#include <hip/hip_bf16.h>

#define TT 512
#define BB 64
#define HH 128
#define GG 512   // 4*H
#define TBH (TT*BB*HH)
#define TBG (TT*BB*GG)
#define BH (BB*HH)
#define CH 64                 // wavefront chunk length (timesteps)
#define NCH (TT/CH)           // 8 chunks
#define CHGG (CH*BB*GG)       // floats per xg chunk slot
#define CHH (CH*BB*HH)        // floats per out chunk

__device__ __forceinline__ float bflo(unsigned u) { return __uint_as_float(u << 16); }
__device__ __forceinline__ float bfhi(unsigned u) { return __uint_as_float(u & 0xffff0000u); }
__device__ __forceinline__ float ldf(const void* p, size_t i, int isbf) {
  return isbf ? __uint_as_float(((unsigned)((const unsigned short*)p)[i]) << 16)
              : ((const float*)p)[i];
}

template<int CTRL>
__device__ __forceinline__ float dpp_add(float v) {
  int r = __builtin_amdgcn_mov_dpp(__float_as_int(v), CTRL, 0xF, 0xF, true);
  return v + __int_as_float(r);
}

__device__ __forceinline__ float sigm(float x) {
  return __builtin_amdgcn_rcpf(1.f + __expf(-x));
}
__device__ __forceinline__ float tanh_f(float x) {
  return fmaf(2.f, __builtin_amdgcn_rcpf(1.f + __expf(-2.f * x)), -1.f);
}

// load 16 consecutive W elements (element offset off, 16-aligned) as 4 float4
__device__ __forceinline__ void ldw16(const void* W, size_t off, int isbf, float4* out) {
  if (isbf) {
    const uint4* wp = (const uint4*)W;
    uint4 v0 = wp[(off >> 3) + 0];
    uint4 v1 = wp[(off >> 3) + 1];
    out[0] = make_float4(bflo(v0.x), bfhi(v0.x), bflo(v0.y), bfhi(v0.y));
    out[1] = make_float4(bflo(v0.z), bfhi(v0.z), bflo(v0.w), bfhi(v0.w));
    out[2] = make_float4(bflo(v1.x), bfhi(v1.x), bflo(v1.y), bfhi(v1.y));
    out[3] = make_float4(bflo(v1.z), bfhi(v1.z), bflo(v1.w), bfhi(v1.w));
  } else {
    const float4* wp = (const float4*)W;
    out[0] = wp[(off >> 2) + 0]; out[1] = wp[(off >> 2) + 1];
    out[2] = wp[(off >> 2) + 2]; out[3] = wp[(off >> 2) + 3];
  }
}

__global__ __launch_bounds__(256) void k_detect(const unsigned* __restrict__ bits,
                                                unsigned* __restrict__ flag) {
  __shared__ int cnt;
  if (threadIdx.x == 0) cnt = 0;
  __syncthreads();
  int local = 0;
  for (int i = threadIdx.x; i < 1024; i += 256) {
    unsigned e = (bits[i] >> 7) & 0xff;
    if (e >= 118 && e <= 134) local++;
  }
  atomicAdd(&cnt, local);
  __syncthreads();
  if (threadIdx.x == 0) *flag = (cnt > 768) ? 1u : 0u;
}

__global__ __launch_bounds__(256) void k_embed(const int* __restrict__ idx,
                                               const void* __restrict__ emb,
                                               const unsigned* __restrict__ flag,
                                               float* __restrict__ x0) {
  int isbf = (int)*flag;
  int i = blockIdx.x * 256 + threadIdx.x;
  int h = i & (HH - 1);
  int tb = i >> 7;
  x0[i] = ldf(emb, (size_t)idx[tb] * HH + h, isbf);
}

// C[M,512] = A[M,K] @ W[512,K]^T + bias ; grid (M/64, 8)   (L0 + fallback path)
__global__ __launch_bounds__(256) void k_proj(const float* __restrict__ A,
                                              const void* __restrict__ W, size_t w_off,
                                              const void* __restrict__ bias, size_t b_off,
                                              float* __restrict__ C, int K,
                                              const unsigned* __restrict__ flag) {
  int isbf = (int)*flag;
  __shared__ float As[16][68];
  __shared__ float Bs[16][68];
  int tid = threadIdx.x;
  int tx = tid & 15, ty = tid >> 4;
  int m_base = blockIdx.x * 64, n_base = blockIdx.y * 64;
  float acc[4][4] = {};
  int kk = tid & 15, rr = tid >> 4;
  for (int k0 = 0; k0 < K; k0 += 16) {
    #pragma unroll
    for (int r = 0; r < 4; r++) {
      As[kk][rr + 16*r] = A[(size_t)(m_base + rr + 16*r) * K + k0 + kk];
      Bs[kk][rr + 16*r] = ldf(W, w_off + (size_t)(n_base + rr + 16*r) * K + k0 + kk, isbf);
    }
    __syncthreads();
    #pragma unroll
    for (int k = 0; k < 16; k++) {
      float4 av = *(const float4*)(&As[k][ty*4]);
      float4 bv = *(const float4*)(&Bs[k][tx*4]);
      float a[4] = {av.x, av.y, av.z, av.w};
      float b[4] = {bv.x, bv.y, bv.z, bv.w};
      #pragma unroll
      for (int i = 0; i < 4; i++)
        #pragma unroll
        for (int j = 0; j < 4; j++)
          acc[i][j] += a[i] * b[j];
    }
    __syncthreads();
  }
  #pragma unroll
  for (int i = 0; i < 4; i++) {
    #pragma unroll
    for (int j = 0; j < 4; j++) {
      int n = n_base + tx*4 + j;
      C[(size_t)(m_base + ty*4 + i) * GG + n] = acc[i][j] + ldf(bias, b_off + n, isbf);
    }
  }
}

// L0 + fallback recurrent kernel (full-T). One block per (batch, direction).
__global__ __launch_bounds__(512, 2) void k_recur(
    const float* __restrict__ xg, size_t xg_dstride,
    const void* __restrict__ whh, size_t w_off, size_t w_dstride,
    float* __restrict__ hout, int hout_stride, int hout_doff,
    const float* __restrict__ res,
    float* __restrict__ hfin, float* __restrict__ cfin,
    int bidir, const unsigned* __restrict__ flag) {
  int isbf = (int)*flag;
  int d = blockIdx.x >> 6;
  int b = blockIdx.x & 63;
  int dir = (bidir == 2 || (bidir == 1 && d)) ? -1 : 1;
  xg += (size_t)d * xg_dstride;
  size_t woff = w_off + (size_t)d * w_dstride;
  int hcol = hout_doff * d;

  int t0 = threadIdx.x;
  int j = t0 >> 2, q = t0 & 3;

  // W_hh fragment, rotated by q chunks for bank-conflict-free broadcast reads
  float w[4][32];
  size_t wbase = woff + (size_t)j * HH + q * 32;
  if (isbf) {
    const uint4* wp = (const uint4*)whh;
    #pragma unroll
    for (int g = 0; g < 4; g++) {
      size_t b8 = (wbase + (size_t)g * 128 * HH) >> 3;
      #pragma unroll
      for (int u = 0; u < 4; u++) {
        uint4 v = wp[b8 + ((u + q) & 3)];
        w[g][u*8+0] = bflo(v.x); w[g][u*8+1] = bfhi(v.x);
        w[g][u*8+2] = bflo(v.y); w[g][u*8+3] = bfhi(v.y);
        w[g][u*8+4] = bflo(v.z); w[g][u*8+5] = bfhi(v.z);
        w[g][u*8+6] = bflo(v.w); w[g][u*8+7] = bfhi(v.w);
      }
    }
  } else {
    const float4* wp = (const float4*)whh;
    #pragma unroll
    for (int g = 0; g < 4; g++) {
      size_t b4 = (wbase + (size_t)g * 128 * HH) >> 2;
      #pragma unroll
      for (int u = 0; u < 8; u++) {
        float4 v = wp[b4 + ((u + 2*q) & 7)];
        w[g][u*4+0] = v.x; w[g][u*4+1] = v.y; w[g][u*4+2] = v.z; w[g][u*4+3] = v.w;
      }
    }
  }

  __shared__ float h_lds[2][HH];
  if (t0 < HH) h_lds[0][t0] = 0.f;
  float c = 0.f;

  int tfirst = (dir > 0) ? 0 : (TT - 1);
  size_t rg0 = ((size_t)tfirst * BB + b) * GG;
  float xg_cur[4];
  #pragma unroll
  for (int g = 0; g < 4; g++) xg_cur[g] = xg[rg0 + g * HH + j];
  float res_cur = res ? res[((size_t)tfirst * BB + b) * HH + j] : 0.f;
  __syncthreads();

  const float* hc = h_lds[0];
  float* hn = h_lds[1];

  #pragma unroll 1
  for (int s = 0; s < TT; s++) {
    int t = (dir > 0) ? s : (TT - 1 - s);
    float xg_nxt[4] = {0.f, 0.f, 0.f, 0.f};
    float res_nxt = 0.f;
    if (s + 1 < TT) {
      int tn = (dir > 0) ? (s + 1) : (TT - 2 - s);
      size_t rg = ((size_t)tn * BB + b) * GG;
      #pragma unroll
      for (int g = 0; g < 4; g++) xg_nxt[g] = xg[rg + g * HH + j];
      if (res) res_nxt = res[((size_t)tn * BB + b) * HH + j];
    }
    float p0 = 0.f, p1 = 0.f, p2 = 0.f, p3 = 0.f;
    const float4* hq = (const float4*)(hc + (q << 5));
    #pragma unroll
    for (int u = 0; u < 8; u++) {
      float4 hv = hq[(u + 2*q) & 7];
      p0 = fmaf(w[0][u*4+0], hv.x, p0); p0 = fmaf(w[0][u*4+1], hv.y, p0);
      p0 = fmaf(w[0][u*4+2], hv.z, p0); p0 = fmaf(w[0][u*4+3], hv.w, p0);
      p1 = fmaf(w[1][u*4+0], hv.x, p1); p1 = fmaf(w[1][u*4+1], hv.y, p1);
      p1 = fmaf(w[1][u*4+2], hv.z, p1); p1 = fmaf(w[1][u*4+3], hv.w, p1);
      p2 = fmaf(w[2][u*4+0], hv.x, p2); p2 = fmaf(w[2][u*4+1], hv.y, p2);
      p2 = fmaf(w[2][u*4+2], hv.z, p2); p2 = fmaf(w[2][u*4+3], hv.w, p2);
      p3 = fmaf(w[3][u*4+0], hv.x, p3); p3 = fmaf(w[3][u*4+1], hv.y, p3);
      p3 = fmaf(w[3][u*4+2], hv.z, p3); p3 = fmaf(w[3][u*4+3], hv.w, p3);
    }
    p0 = dpp_add<0xB1>(p0); p0 = dpp_add<0x4E>(p0);
    p1 = dpp_add<0xB1>(p1); p1 = dpp_add<0x4E>(p1);
    p2 = dpp_add<0xB1>(p2); p2 = dpp_add<0x4E>(p2);
    p3 = dpp_add<0xB1>(p3); p3 = dpp_add<0x4E>(p3);

    float gi = p0 + xg_cur[0], gf = p1 + xg_cur[1];
    float gc = p2 + xg_cur[2], go = p3 + xg_cur[3];
    float si = sigm(gi), sf = sigm(gf), so = sigm(go);
    c = fmaf(sf, c, si * tanh_f(gc));
    float h = so * tanh_f(c);

    if (q == 0) {
      hn[j] = h;
      hout[((size_t)t * BB + b) * hout_stride + hcol + j] = h + res_cur;
      if (t == TT - 1) hfin[(size_t)(d * BB + b) * HH + j] = h;
    }
    #pragma unroll
    for (int g = 0; g < 4; g++) xg_cur[g] = xg_nxt[g];
    res_cur = res_nxt;
    __syncthreads();
    const float* tmp = hc; hc = hn; hn = (float*)tmp;
  }
  if (q == 0) cfin[(size_t)(d * BB + b) * HH + j] = c;
}

// ---------------- wavefront kernel: layers 1..7, chunked, lag-1 ----------------
// Cell recur(r,k) at wave r-1+k (waves 0..13). Per block (one (cell, batch)):
//   [r==1]  prologue: stage xcat chunk (256 cols) in LDS; xg(1,k) -> scratch (global)
//   recur: 64 steps; writes out chunk (ring / out7), fills hchunk[64][.] (layer output)
//   [r<7]   epilogue: xg(r+1,k) = hchunk @ w_ih(r+1)^T + b -> slot (layer,parity keyed)
// GEMM tiling (spill-free): thread owns 4 columns {nn,nn+128,nn+256,nn+384}, 16 m-rows
// (mh=t0>>7). Per K-chunk of 16: wcb[4][4] (64 regs) + acc[4][16] (64 regs); each LDS
// broadcast read feeds 16 FMAs. No barriers inside the GEMM.
struct WaveDesc { int n; int r[8]; int k[8]; };

__device__ __forceinline__ void colgemm4(
    const float (*hch)[264], int K,
    const void* W, size_t wbase,            // element offset of row 0 (row = col, width K)
    const void* bias, size_t bias_off, int isbf,
    float* dstbase, int nn, int mh) {       // dst element = dstbase + m*BB*GG + col
  float acc[4][16];
  #pragma unroll
  for (int c = 0; c < 4; c++) {
    float bv = ldf(bias, bias_off + nn + 128*c, isbf);
    #pragma unroll
    for (int mi = 0; mi < 16; mi++) acc[c][mi] = bv;
  }
  #pragma unroll 1
  for (int kb = 0; kb < K; kb += 16) {
    float4 wcb[4][4];
    #pragma unroll
    for (int c = 0; c < 4; c++)
      ldw16(W, wbase + (size_t)(nn + 128*c) * K + kb, isbf, wcb[c]);
    #pragma unroll
    for (int mi = 0; mi < 16; mi++) {
      const float* hrow = &hch[mh*16 + mi][kb];
      float4 hv[4];
      hv[0] = *(const float4*)&hrow[0];
      hv[1] = *(const float4*)&hrow[4];
      hv[2] = *(const float4*)&hrow[8];
      hv[3] = *(const float4*)&hrow[12];
      #pragma unroll
      for (int c = 0; c < 4; c++) {
        #pragma unroll
        for (int u = 0; u < 4; u++) {
          acc[c][mi] = fmaf(wcb[c][u].x, hv[u].x, acc[c][mi]);
          acc[c][mi] = fmaf(wcb[c][u].y, hv[u].y, acc[c][mi]);
          acc[c][mi] = fmaf(wcb[c][u].z, hv[u].z, acc[c][mi]);
          acc[c][mi] = fmaf(wcb[c][u].w, hv[u].w, acc[c][mi]);
        }
      }
    }
  }
  #pragma unroll
  for (int mi = 0; mi < 16; mi++) {
    size_t mo = (size_t)(mh*16 + mi) * BB * GG;
    #pragma unroll
    for (int c = 0; c < 4; c++)
      dstbase[mo + nn + 128*c] = acc[c][mi];
  }
}

__global__ __launch_bounds__(512, 1) void k_wave(
    WaveDesc wd, float* __restrict__ xgf, float* __restrict__ xgb,
    const float* __restrict__ xcat, float* __restrict__ out7, float* __restrict__ scratch,
    const void* __restrict__ w_ih1, const void* __restrict__ w_hh1, const void* __restrict__ b1,
    const void* __restrict__ w_ihr, const void* __restrict__ w_hhr, const void* __restrict__ br,
    const unsigned* __restrict__ flag) {
  int isbf = (int)*flag;
  int slot = blockIdx.x >> 6;
  int b = blockIdx.x & 63;
  int r = wd.r[slot];
  int k = wd.k[slot];

  float* ringbase = xgb + 4 * (size_t)CHGG;          // 12 x CHH (layers 1..6, ring-2)
  float* hstate   = ringbase + 12 * (size_t)CHH;     // [7][BB][HH]
  float* cstate   = hstate + 7 * (size_t)BH;

  auto xgslot = [&](int rr, int kk) -> float* {      // rr in [2,7]
    int s = (rr - 2) * 2 + (kk & 1);
    return (s < 8) ? (xgf + (size_t)s * CHGG) : (xgb + (size_t)(s - 8) * CHGG);
  };
  auto ringch = [&](int rr, int kk) -> float* {      // rr in [1,6]
    return ringbase + ((size_t)(rr - 1) * 2 + (kk & 1)) * CHH;
  };

  __shared__ float hchunk[CH][264];   // layer-input/-output chunk (up to 256 cols)
  __shared__ float h_lds[2][HH];

  int t0 = threadIdx.x;
  int nn = t0 & 127;                  // GEMM column base
  int mh = t0 >> 7;                   // GEMM m-tile (16 rows)

  // -------- layer-1 prologue: xg(1,k) -> scratch (K=256, single pass) --------
  if (r == 1) {
    {
      int m = t0 >> 3, c0 = (t0 & 7) * 32;
      const float* src = xcat + ((size_t)(k * CH + m) * BB + b) * (2 * HH) + c0;
      #pragma unroll
      for (int u = 0; u < 8; u++)
        *(float4*)&hchunk[m][c0 + u * 4] = ((const float4*)src)[u];
    }
    __syncthreads();
    colgemm4(hchunk, 2 * HH, w_ih1, 0, b1, 0, isbf,
             scratch + (size_t)b * GG, nn, mh);
    __syncthreads();   // make scratch stores visible to all threads' xg reads below
  }

  // -------- recur: chunk k of layer r --------
  const void* whh = (r == 1) ? w_hh1 : w_hhr;
  size_t woff = (r == 1) ? 0 : (size_t)(r - 2) * GG * HH;
  const float* xg = (r == 1) ? scratch : xgslot(r, k);
  const float* resb = (r >= 2) ? (ringch(r - 1, k) + (size_t)b * HH) : nullptr;
  float* houtb = (r == 7) ? (out7 + (size_t)k * CHH + (size_t)b * HH)
                          : (ringch(r, k) + (size_t)b * HH);
  float* hst = hstate + (size_t)(r - 1) * BH + (size_t)b * HH;
  float* cst = cstate + (size_t)(r - 1) * BH + (size_t)b * HH;

  int j = t0 >> 2, q = t0 & 3;

  float w[4][32];
  size_t wbase = woff + (size_t)j * HH + q * 32;
  if (isbf) {
    const uint4* wp = (const uint4*)whh;
    #pragma unroll
    for (int g = 0; g < 4; g++) {
      size_t b8 = (wbase + (size_t)g * 128 * HH) >> 3;
      #pragma unroll
      for (int u = 0; u < 4; u++) {
        uint4 v = wp[b8 + ((u + q) & 3)];
        w[g][u*8+0] = bflo(v.x); w[g][u*8+1] = bfhi(v.x);
        w[g][u*8+2] = bflo(v.y); w[g][u*8+3] = bfhi(v.y);
        w[g][u*8+4] = bflo(v.z); w[g][u*8+5] = bfhi(v.z);
        w[g][u*8+6] = bflo(v.w); w[g][u*8+7] = bfhi(v.w);
      }
    }
  } else {
    const float4* wp = (const float4*)whh;
    #pragma unroll
    for (int g = 0; g < 4; g++) {
      size_t b4 = (wbase + (size_t)g * 128 * HH) >> 2;
      #pragma unroll
      for (int u = 0; u < 8; u++) {
        float4 v = wp[b4 + ((u + 2*q) & 7)];
        w[g][u*4+0] = v.x; w[g][u*4+1] = v.y; w[g][u*4+2] = v.z; w[g][u*4+3] = v.w;
      }
    }
  }

  if (t0 < HH) h_lds[0][t0] = k ? hst[t0] : 0.f;
  float c = k ? cst[j] : 0.f;

  size_t rg0 = (size_t)b * GG;  // t_loc = 0
  float xg_cur[4];
  #pragma unroll
  for (int g = 0; g < 4; g++) xg_cur[g] = xg[rg0 + g * HH + j];
  float res_cur = resb ? resb[j] : 0.f;
  __syncthreads();

  const float* hc = h_lds[0];
  float* hn = h_lds[1];

  #pragma unroll 1
  for (int s = 0; s < CH; s++) {
    float xg_nxt[4] = {0.f, 0.f, 0.f, 0.f};
    float res_nxt = 0.f;
    if (s + 1 < CH) {
      size_t rg = ((size_t)(s + 1) * BB + b) * GG;
      #pragma unroll
      for (int g = 0; g < 4; g++) xg_nxt[g] = xg[rg + g * HH + j];
      if (resb) res_nxt = resb[(size_t)(s + 1) * BB * HH + j];
    }
    float p0 = 0.f, p1 = 0.f, p2 = 0.f, p3 = 0.f;
    const float4* hq = (const float4*)(hc + (q << 5));
    #pragma unroll
    for (int u = 0; u < 8; u++) {
      float4 hv = hq[(u + 2*q) & 7];
      p0 = fmaf(w[0][u*4+0], hv.x, p0); p0 = fmaf(w[0][u*4+1], hv.y, p0);
      p0 = fmaf(w[0][u*4+2], hv.z, p0); p0 = fmaf(w[0][u*4+3], hv.w, p0);
      p1 = fmaf(w[1][u*4+0], hv.x, p1); p1 = fmaf(w[1][u*4+1], hv.y, p1);
      p1 = fmaf(w[1][u*4+2], hv.z, p1); p1 = fmaf(w[1][u*4+3], hv.w, p1);
      p2 = fmaf(w[2][u*4+0], hv.x, p2); p2 = fmaf(w[2][u*4+1], hv.y, p2);
      p2 = fmaf(w[2][u*4+2], hv.z, p2); p2 = fmaf(w[2][u*4+3], hv.w, p2);
      p3 = fmaf(w[3][u*4+0], hv.x, p3); p3 = fmaf(w[3][u*4+1], hv.y, p3);
      p3 = fmaf(w[3][u*4+2], hv.z, p3); p3 = fmaf(w[3][u*4+3], hv.w, p3);
    }
    p0 = dpp_add<0xB1>(p0); p0 = dpp_add<0x4E>(p0);
    p1 = dpp_add<0xB1>(p1); p1 = dpp_add<0x4E>(p1);
    p2 = dpp_add<0xB1>(p2); p2 = dpp_add<0x4E>(p2);
    p3 = dpp_add<0xB1>(p3); p3 = dpp_add<0x4E>(p3);

    float gi = p0 + xg_cur[0], gf = p1 + xg_cur[1];
    float gc = p2 + xg_cur[2], go = p3 + xg_cur[3];
    float si = sigm(gi), sf = sigm(gf), so = sigm(go);
    c = fmaf(sf, c, si * tanh_f(gc));
    float h = so * tanh_f(c);

    if (q == 0) {
      float hv = h + res_cur;
      hn[j] = h;
      hchunk[s][j] = hv;
      houtb[(size_t)s * BB * HH + j] = hv;
      if (s == CH - 1) hst[j] = h;   // raw h for next chunk's state
    }
    #pragma unroll
    for (int g = 0; g < 4; g++) xg_cur[g] = xg_nxt[g];
    res_cur = res_nxt;
    __syncthreads();
    const float* tmp = hc; hc = hn; hn = (float*)tmp;
  }
  if (q == 0) cst[j] = c;

  // -------- epilogue: xg(r+1,k) = hchunk @ w_ih(r+1)^T + b  (K=128, no barriers) --------
  // hchunk writes are covered by the loop's final __syncthreads.
  if (r < 7) {
    colgemm4(hchunk, HH, w_ihr, (size_t)(r - 1) * GG * HH,
             br, (size_t)(r - 1) * GG, isbf,
             xgslot(r + 1, k) + (size_t)b * GG, nn, mh);
  }
}

__global__ __launch_bounds__(256) void k_out(const float* __restrict__ x,
                                             const float* __restrict__ hfin,
                                             const float* __restrict__ cfin,
                                             void* __restrict__ out,
                                             const unsigned* __restrict__ flag) {
  int isbf = (int)*flag;
  int i = blockIdx.x * 256 + threadIdx.x;
  float v;
  if (i < TBH) v = x[i];
  else if (i < TBH + BH) v = hfin[i - TBH];
  else v = cfin[i - TBH - BH];
  if (isbf) ((__hip_bfloat16*)out)[i] = __float2bfloat16(v);
  else ((float*)out)[i] = v;
}

extern "C" void kernel_launch(void* const* d_in, const int* in_sizes, int n_in,
                              void* d_out, int out_size, void* d_ws, size_t ws_size,
                              hipStream_t stream) {
  const int* idx = (const int*)d_in[0];
  const void* emb   = d_in[1];
  const void* w_ih0 = d_in[2];
  const void* w_hh0 = d_in[3];
  const void* b0    = d_in[4];
  const void* w_ih1 = d_in[5];
  const void* w_hh1 = d_in[6];
  const void* b1    = d_in[7];
  const void* w_ihr = d_in[8];
  const void* w_hhr = d_in[9];
  const void* br    = d_in[10];

  float* ws   = (float*)d_ws;
  float* x0   = ws;                       // TBH   (L0 input; later out7; chunks 4..7 = scratch)
  float* xcat = ws + TBH;                 // 2*TBH (L0 output / L1 input, live through wave 7)
  float* xg_f = ws + 3 * (size_t)TBH;     // TBG   (L0 fwd xg; later xg slots 0..7)
  float* hfin = ws + 3 * (size_t)TBH + TBG;        // 2*BH
  float* cfin = hfin + 2 * BH;                     // 2*BH
  unsigned* flag = (unsigned*)(cfin + 2 * BH);
  float* xg_b = cfin + 2 * BH + 16384;    // TBG (L0 bwd xg; later slots 8..11 + rings + states)
  int merged = ws_size >= (size_t)(3 * (size_t)TBH + 2 * (size_t)TBG + 4 * BH + 16384 + 64) * 4;

  k_detect<<<1, 256, 0, stream>>>((const unsigned*)emb, flag);
  k_embed<<<TBH / 256, 256, 0, stream>>>(idx, emb, flag, x0);

  dim3 pg(512, 8);
  if (merged) {
    // ---- layer 0 (bidirectional) ----
    k_proj<<<pg, 256, 0, stream>>>(x0, w_ih0, 0, b0, 0, xg_f, HH, flag);
    k_proj<<<pg, 256, 0, stream>>>(x0, w_ih0, (size_t)GG * HH, b0, GG, xg_b, HH, flag);
    k_recur<<<128, 512, 0, stream>>>(xg_f, (size_t)(xg_b - xg_f), w_hh0, 0, (size_t)GG * HH,
                                     xcat, 2 * HH, HH, nullptr, hfin, cfin, 1, flag);

    // ---- layers 1..7: lag-1 wavefront ----
    float* scratch = x0 + (size_t)TBH / 2;             // = one CHGG, aliases out7 chunks 4..7
    float* ringbase = xg_b + 4 * (size_t)CHGG;
    float* hstate  = ringbase + 12 * (size_t)CHH;
    float* cstate  = hstate + 7 * (size_t)BH;
    for (int wv = 0; wv <= 6 + (NCH - 1); wv++) {
      WaveDesc wd; wd.n = 0;
      for (int r = 1; r <= 7; r++) {                   // r ascending: layer-1 (heaviest) first
        int kk = wv - (r - 1);
        if (kk >= 0 && kk < NCH) { wd.r[wd.n] = r; wd.k[wd.n] = kk; wd.n++; }
      }
      if (wd.n)
        k_wave<<<wd.n * 64, 512, 0, stream>>>(wd, xg_f, xg_b, xcat, x0, scratch,
                                              w_ih1, w_hh1, b1, w_ihr, w_hhr, br, flag);
    }
    k_out<<<(TBH + 2 * BH) / 256, 256, 0, stream>>>(x0, hstate + 6 * BH, cstate + 6 * BH,
                                                    d_out, flag);
  } else {
    // ---- fallback: original fully-serial path ----
    k_proj<<<pg, 256, 0, stream>>>(x0, w_ih0, 0, b0, 0, xg_f, HH, flag);
    k_recur<<<64, 512, 0, stream>>>(xg_f, 0, w_hh0, 0, 0,
                                    xcat, 2 * HH, 0, nullptr, hfin, cfin, 0, flag);
    k_proj<<<pg, 256, 0, stream>>>(x0, w_ih0, (size_t)GG * HH, b0, GG, xg_f, HH, flag);
    k_recur<<<64, 512, 0, stream>>>(xg_f, 0, w_hh0, (size_t)GG * HH, 0,
                                    xcat + HH, 2 * HH, 0, nullptr, hfin, cfin, 2, flag);
    float* xA = xcat;
    float* xB = xcat + TBH;
    k_proj<<<pg, 256, 0, stream>>>(xcat, w_ih1, 0, b1, 0, xg_f, 2 * HH, flag);
    k_recur<<<64, 512, 0, stream>>>(xg_f, 0, w_hh1, 0, 0, xA, HH, 0, nullptr, hfin, cfin, 0, flag);
    float* cur = xA;
    float* nxt = xB;
    for (int r = 0; r < 6; r++) {
      k_proj<<<pg, 256, 0, stream>>>(cur, w_ihr, (size_t)r * GG * HH, br, (size_t)r * GG, xg_f, HH, flag);
      k_recur<<<64, 512, 0, stream>>>(xg_f, 0, w_hhr, (size_t)r * GG * HH, 0,
                                      nxt, HH, 0, cur, hfin, cfin, 0, flag);
      float* t = cur; cur = nxt; nxt = t;
    }
    k_out<<<(TBH + 2 * BH) / 256, 256, 0, stream>>>(cur, hfin, cfin, d_out, flag);
  }
}